// Round 5
// baseline (872.583 us; speedup 1.0000x reference)
//
#include <hip/hip_runtime.h>
#include <math.h>

#define NEG_SLOPE 0.2f

typedef __bf16 bf16x8 __attribute__((ext_vector_type(8)));
typedef float f32x4 __attribute__((ext_vector_type(4)));

// f32 -> bf16 bits, round-to-nearest-even
__device__ __forceinline__ ushort f2bf(float x) {
  union { float f; unsigned u; } v; v.f = x;
  unsigned r = v.u + 0x7fffu + ((v.u >> 16) & 1u);
  return (ushort)(r >> 16);
}
__device__ __forceinline__ float bf2f(ushort b) {
  union { unsigned u; float f; } v; v.u = (unsigned)b << 16;
  return v.f;
}

// LDS swizzle for [32][512B] rows (XORs byte bits 4-8 by row)
__device__ __forceinline__ int swz(int m) {
  return ((m & 7) << 4) | (((m >> 3) & 3) << 7);
}

// atomic float max via int/uint trick (works for mixed signs, init -inf)
__device__ __forceinline__ void atomicMaxF32(float* addr, float val) {
  if (val >= 0.f) {
    atomicMax((int*)addr, __float_as_int(val));
  } else {
    atomicMin((unsigned int*)addr, __float_as_uint(val));
  }
}

// ---------------- K0: init emax=-inf, asum=0, agg=0 ----------------
__global__ void k_init(float* __restrict__ emax, float* __restrict__ asum,
                       float* __restrict__ agg, int n) {
  int i = blockIdx.x * 256 + threadIdx.x;
  if (i < n * 4) { emax[i] = -INFINITY; asum[i] = 0.f; }
  if (i < n * 64) agg[i] = 0.f;
}

// ---------------- K prep: transpose weights to bf16 ----------------
__global__ void k_prep(const float* __restrict__ Wfij,
                       const float* __restrict__ Wpe,
                       ushort* __restrict__ WfT, ushort* __restrict__ WpeT) {
  int i = blockIdx.x * 256 + threadIdx.x;
  if (i < 16384) {
    int k = i >> 8, c = i & 255;   // Wfij[k][c]
    WfT[c * 64 + k] = f2bf(Wfij[i]);
    int k2 = i >> 6, n2 = i & 63;  // Wpe[k2][n2]
    WpeT[n2 * 256 + k2] = f2bf(Wpe[i]);
  }
}

// ---------------- K1: node transforms: ni(bf16), nj(bf16), hq(f32) ----------------
__global__ __launch_bounds__(256) void k_node(
    const float* __restrict__ hE,
    const float* __restrict__ Wni, const float* __restrict__ Wnj,
    const float* __restrict__ Wnode, const float* __restrict__ bnode,
    const float* __restrict__ Wpn,
    ushort* __restrict__ ni_bf, ushort* __restrict__ nj_bf,
    float* __restrict__ hq, int n) {
  __shared__ float hEt[64 * 36];    // transposed [k][m], stride 36 (pad)
  __shared__ float hpl[32 * 260];   // hp tile [m][c], stride 260 (pad)
  const int tid = threadIdx.x;
  const int n0 = blockIdx.x * 32;

#pragma unroll
  for (int i = 0; i < 8; ++i) {
    int flat = tid + i * 256;
    int m = flat >> 6, k = flat & 63;
    hEt[k * 36 + m] = (n0 + m < n) ? hE[(size_t)(n0 + m) * 64 + k] : 0.f;
  }
  __syncthreads();

  const int tm = tid >> 5, tc = tid & 31, c0 = tc * 8;

  for (int pass = 0; pass < 3; ++pass) {
    const float* W = (pass == 0) ? Wni : (pass == 1) ? Wnj : Wnode;
    float acc[4][8];
#pragma unroll
    for (int mm = 0; mm < 4; ++mm)
#pragma unroll
      for (int j = 0; j < 8; ++j) acc[mm][j] = 0.f;

    for (int k = 0; k < 64; ++k) {
      float4 h4 = *(const float4*)&hEt[k * 36 + tm * 4];
      float4 w0 = *(const float4*)&W[k * 256 + c0];
      float4 w1 = *(const float4*)&W[k * 256 + c0 + 4];
      float hv[4] = {h4.x, h4.y, h4.z, h4.w};
      float wv[8] = {w0.x, w0.y, w0.z, w0.w, w1.x, w1.y, w1.z, w1.w};
#pragma unroll
      for (int mm = 0; mm < 4; ++mm)
#pragma unroll
        for (int j = 0; j < 8; ++j) acc[mm][j] += hv[mm] * wv[j];
    }

    if (pass < 2) {
      ushort* out = (pass == 0) ? ni_bf : nj_bf;
#pragma unroll
      for (int mm = 0; mm < 4; ++mm) {
        int m = tm * 4 + mm;
        if (n0 + m < n) {
          ushort u[8];
#pragma unroll
          for (int j = 0; j < 8; ++j) u[j] = f2bf(acc[mm][j]);
          *(uint4*)&out[(size_t)(n0 + m) * 256 + c0] = *(const uint4*)u;
        }
      }
    } else {
#pragma unroll
      for (int mm = 0; mm < 4; ++mm) {
        int m = tm * 4 + mm;
#pragma unroll
        for (int j = 0; j < 8; ++j)
          hpl[m * 260 + c0 + j] = acc[mm][j] + bnode[c0 + j];
      }
    }
  }
  __syncthreads();

  // hq pass: per-head 64x64 projection. col c0+j lives in head hh.
  const int hh = tc >> 3, dc0 = (tc & 7) * 8;
  float acc[4][8];
#pragma unroll
  for (int mm = 0; mm < 4; ++mm)
#pragma unroll
    for (int j = 0; j < 8; ++j) acc[mm][j] = 0.f;

  for (int k = 0; k < 64; ++k) {
    float4 w0 = *(const float4*)&Wpn[(size_t)(hh * 64 + k) * 64 + dc0];
    float4 w1 = *(const float4*)&Wpn[(size_t)(hh * 64 + k) * 64 + dc0 + 4];
    float wv[8] = {w0.x, w0.y, w0.z, w0.w, w1.x, w1.y, w1.z, w1.w};
#pragma unroll
    for (int mm = 0; mm < 4; ++mm) {
      float hv = hpl[(tm * 4 + mm) * 260 + hh * 64 + k];
#pragma unroll
      for (int j = 0; j < 8; ++j) acc[mm][j] += hv * wv[j];
    }
  }
#pragma unroll
  for (int mm = 0; mm < 4; ++mm) {
    int m = tm * 4 + mm;
    if (n0 + m < n) {
      *(float4*)&hq[(size_t)(n0 + m) * 256 + c0] =
          make_float4(acc[mm][0], acc[mm][1], acc[mm][2], acc[mm][3]);
      *(float4*)&hq[(size_t)(n0 + m) * 256 + c0 + 4] =
          make_float4(acc[mm][4], acc[mm][5], acc[mm][6], acc[mm][7]);
    }
  }
}

// ---------------- K2: edge kernel (transposed GEMM1, reg-resident gather) ----
// GEMM1 computes f^T via mfma(WfT_frag, hH_frag): D col = edge m, row = c.
// Each lane then owns 4 consecutive c per frag -> g gathered as 8B uint2
// straight into registers (no LDS staging, no extra barrier).
// f written to LDS (bf16, [32][256] swizzled) only as GEMM2's A operand.
// One barrier per block. Tile: 32 edges, 4 waves; wave w owns head w
// (GEMM1 c-slab [w*64,w*64+64)) and GEMM2 d-cols [w*16,w*16+16).
__global__ __launch_bounds__(256) void k_edge(
    const float* __restrict__ hH,
    const int* __restrict__ src, const int* __restrict__ dst,
    const ushort* __restrict__ WfT,   // [256][64] bf16
    const float* __restrict__ attn,
    const ushort* __restrict__ WpeT,  // [64][256] bf16
    const float* __restrict__ bpe,
    const ushort* __restrict__ ni_bf, const ushort* __restrict__ nj_bf,
    float* __restrict__ e_ws, float* __restrict__ emax,
    float* __restrict__ out1) {
  __shared__ __align__(16) ushort f_lds[32 * 256];  // 16KB swizzled 512B rows
  char* fb = (char*)f_lds;

  const int tid = threadIdx.x;
  const int e0 = blockIdx.x * 32;
  const int w = tid >> 6, l = tid & 63;
  const int lr = l & 15, lk = l >> 4;
  const int cbase = w * 64 + lk * 4;  // lane's base feature column

  int sn[2], dn[2];
  sn[0] = src[e0 + lr];      dn[0] = dst[e0 + lr];
  sn[1] = src[e0 + 16 + lr]; dn[1] = dst[e0 + 16 + lr];

  // ---- issue g gathers early: 16 x 8B random loads, hidden under GEMM1
  uint2 gi[2][4], gj[2][4];
#pragma unroll
  for (int mt = 0; mt < 2; ++mt)
#pragma unroll
    for (int ct = 0; ct < 4; ++ct) {
      gi[mt][ct] =
          *(const uint2*)(ni_bf + (size_t)sn[mt] * 256 + cbase + ct * 16);
      gj[mt][ct] =
          *(const uint2*)(nj_bf + (size_t)dn[mt] * 256 + cbase + ct * 16);
    }

  // ---- GEMM1 (transposed): acc[mt][ct] = f^T tile; A=WfT rows(c), B=hH rows(m)
  f32x4 acc[2][4];
#pragma unroll
  for (int mt = 0; mt < 2; ++mt)
#pragma unroll
    for (int ct = 0; ct < 4; ++ct) acc[mt][ct] = (f32x4){0.f, 0.f, 0.f, 0.f};

#pragma unroll
  for (int ks = 0; ks < 2; ++ks) {
    bf16x8 bh[2];
#pragma unroll
    for (int mt = 0; mt < 2; ++mt) {
      const float* ap =
          hH + (size_t)(e0 + mt * 16 + lr) * 64 + ks * 32 + lk * 8;
      float4 x = *(const float4*)ap;
      float4 y = *(const float4*)(ap + 4);
      bh[mt][0] = (__bf16)x.x; bh[mt][1] = (__bf16)x.y;
      bh[mt][2] = (__bf16)x.z; bh[mt][3] = (__bf16)x.w;
      bh[mt][4] = (__bf16)y.x; bh[mt][5] = (__bf16)y.y;
      bh[mt][6] = (__bf16)y.z; bh[mt][7] = (__bf16)y.w;
    }
#pragma unroll
    for (int ct = 0; ct < 4; ++ct) {
      bf16x8 aw = *(const bf16x8*)(WfT +
          (size_t)(w * 64 + ct * 16 + lr) * 64 + ks * 32 + lk * 8);
      acc[0][ct] =
          __builtin_amdgcn_mfma_f32_16x16x32_bf16(aw, bh[0], acc[0][ct], 0, 0, 0);
      acc[1][ct] =
          __builtin_amdgcn_mfma_f32_16x16x32_bf16(aw, bh[1], acc[1][ct], 0, 0, 0);
    }
  }

  // ---- +g (registers), leaky, logits, pack f -> LDS (8 x ds_write_b64)
#pragma unroll
  for (int mt = 0; mt < 2; ++mt) {
    int m = mt * 16 + lr;
    int sw = swz(m);
    float p = 0.f;
#pragma unroll
    for (int ct = 0; ct < 4; ++ct) {
      float4 av = *(const float4*)&attn[cbase + ct * 16];
      const ushort* giu = (const ushort*)&gi[mt][ct];
      const ushort* gju = (const ushort*)&gj[mt][ct];
      ushort fu[4];
#pragma unroll
      for (int r = 0; r < 4; ++r) {
        float v = acc[mt][ct][r] + bf2f(giu[r]) + bf2f(gju[r]);
        v = (v >= 0.f) ? v : NEG_SLOPE * v;
        p += v * (&av.x)[r];
        fu[r] = f2bf(v);
      }
      *(uint2*)(fb + m * 512 + (((cbase + ct * 16) * 2) ^ sw)) =
          *(const uint2*)fu;
    }
    p += __shfl_xor(p, 16);
    p += __shfl_xor(p, 32);
    if (lk == 0) {
      e_ws[(size_t)(e0 + m) * 4 + w] = p;
      atomicMaxF32(&emax[(size_t)dn[mt] * 4 + w], p);
    }
  }
  __syncthreads();

  // ---- GEMM2: out1 = f @ Wpe; wave w owns cols [w*16, w*16+16)
  f32x4 acc2[2];
  acc2[0] = (f32x4){0.f, 0.f, 0.f, 0.f};
  acc2[1] = (f32x4){0.f, 0.f, 0.f, 0.f};
  const ushort* bpW = WpeT + (size_t)(w * 16 + lr) * 256;
  const int sw0 = swz(lr), sw1 = swz(16 + lr);
#pragma unroll
  for (int ks = 0; ks < 8; ++ks) {
    int ko = (ks * 32 + lk * 8) * 2;
    bf16x8 b = *(const bf16x8*)(bpW + ks * 32 + lk * 8);
    bf16x8 a0 = *(const bf16x8*)(fb + lr * 512 + (ko ^ sw0));
    bf16x8 a1 = *(const bf16x8*)(fb + (16 + lr) * 512 + (ko ^ sw1));
    acc2[0] = __builtin_amdgcn_mfma_f32_16x16x32_bf16(a0, b, acc2[0], 0, 0, 0);
    acc2[1] = __builtin_amdgcn_mfma_f32_16x16x32_bf16(a1, b, acc2[1], 0, 0, 0);
  }

  // epilogue: + hH + bpe
  float bpv = bpe[w * 16 + lr];
#pragma unroll
  for (int mt = 0; mt < 2; ++mt)
#pragma unroll
    for (int r = 0; r < 4; ++r) {
      int m = mt * 16 + lk * 4 + r;
      size_t idx = (size_t)(e0 + m) * 64 + w * 16 + lr;
      out1[idx] = acc2[mt][r] + hH[idx] + bpv;
    }
}

// ---------------- K3a: a = exp(e - emax[dst]); asum += a ----------------
__global__ void k3a(const float* __restrict__ e_ws, const int* __restrict__ dst,
                    const float* __restrict__ emax, float* __restrict__ a_ws,
                    float* __restrict__ asum, int E4) {
  int gid = blockIdx.x * 256 + threadIdx.x;
  if (gid >= E4) return;
  int e = gid >> 2, h = gid & 3;
  int dn = dst[e];
  float av = expf(e_ws[gid] - emax[dn * 4 + h]);
  a_ws[gid] = av;
  atomicAdd(&asum[dn * 4 + h], av);
}

// ---------------- K3b: agg[dst] += sum_h (a/asum) * hq[src,h,:] ----------------
__global__ __launch_bounds__(256) void k3b(
    const float* __restrict__ a_ws, const float* __restrict__ asum,
    const int* __restrict__ src, const int* __restrict__ dst,
    const float* __restrict__ hq, float* __restrict__ agg, int E) {
  int e = blockIdx.x * 4 + (threadIdx.x >> 6);
  if (e >= E) return;
  int d = threadIdx.x & 63;
  int sn = src[e], dn = dst[e];
  float w0 = a_ws[e * 4 + 0] / asum[dn * 4 + 0];
  float w1 = a_ws[e * 4 + 1] / asum[dn * 4 + 1];
  float w2 = a_ws[e * 4 + 2] / asum[dn * 4 + 2];
  float w3 = a_ws[e * 4 + 3] / asum[dn * 4 + 3];
  const float* hqp = &hq[(size_t)sn * 256];
  float y = w0 * hqp[d] + w1 * hqp[64 + d] + w2 * hqp[128 + d] + w3 * hqp[192 + d];
  atomicAdd(&agg[(size_t)dn * 64 + d], y);
}

// ---------------- K4: out0 = hE + agg + bp_node ----------------
__global__ void k4(const float* __restrict__ hE, const float* __restrict__ agg,
                   const float* __restrict__ bpn, float* __restrict__ out0,
                   int ND) {
  int i = blockIdx.x * 256 + threadIdx.x;
  if (i < ND) out0[i] = hE[i] + agg[i] + bpn[i & 63];
}

extern "C" void kernel_launch(void* const* d_in, const int* in_sizes, int n_in,
                              void* d_out, int out_size, void* d_ws, size_t ws_size,
                              hipStream_t stream) {
  const float* h_E    = (const float*)d_in[0];
  const float* h_H    = (const float*)d_in[1];
  const int*   src    = (const int*)d_in[2];
  const int*   dst    = (const int*)d_in[3];
  const float* W_node = (const float*)d_in[4];
  const float* b_node = (const float*)d_in[5];
  const float* W_ni   = (const float*)d_in[6];
  const float* W_nj   = (const float*)d_in[7];
  const float* W_fij  = (const float*)d_in[8];
  const float* attn   = (const float*)d_in[9];
  const float* Wp_node= (const float*)d_in[10];
  const float* bp_node= (const float*)d_in[11];
  const float* Wp_edge= (const float*)d_in[12];
  const float* bp_edge= (const float*)d_in[13];

  const int n = in_sizes[0] / 64;   // 50000 nodes
  const int e = in_sizes[1] / 64;   // 800000 edges

  // workspace layout
  ushort* ws_ni  = (ushort*)d_ws;                     // n*256 bf16
  ushort* ws_nj  = ws_ni + (size_t)n * 256;           // n*256 bf16
  float*  ws_hq  = (float*)(ws_nj + (size_t)n * 256); // n*256 f32
  float*  ws_e   = ws_hq + (size_t)n * 256;           // e*4
  float*  ws_a   = ws_e + (size_t)e * 4;              // e*4
  float*  ws_emax= ws_a + (size_t)e * 4;              // n*4
  float*  ws_asum= ws_emax + (size_t)n * 4;           // n*4
  float*  ws_agg = ws_asum + (size_t)n * 4;           // n*64
  ushort* ws_WfT = (ushort*)(ws_agg + (size_t)n * 64);// 256*64 bf16
  ushort* ws_WpeT= ws_WfT + 16384;                    // 64*256 bf16

  float* out0 = (float*)d_out;               // (n,64)
  float* out1 = out0 + (size_t)n * 64;       // (e,64)

  {
    int total = n * 64;
    k_init<<<(total + 255) / 256, 256, 0, stream>>>(ws_emax, ws_asum, ws_agg, n);
  }
  k_prep<<<64, 256, 0, stream>>>(W_fij, Wp_edge, ws_WfT, ws_WpeT);
  {
    int blocks = (n + 31) / 32;
    k_node<<<blocks, 256, 0, stream>>>(h_E, W_ni, W_nj, W_node, b_node, Wp_node,
                                       ws_ni, ws_nj, ws_hq, n);
  }
  {
    int blocks = e / 32;  // E=800000 divisible by 32
    k_edge<<<blocks, 256, 0, stream>>>(h_H, src, dst, ws_WfT, attn, ws_WpeT,
                                       bp_edge, ws_ni, ws_nj, ws_e, ws_emax,
                                       out1);
  }
  {
    int total = e * 4;
    k3a<<<(total + 255) / 256, 256, 0, stream>>>(ws_e, dst, ws_emax, ws_a,
                                                 ws_asum, total);
  }
  {
    int blocks = (e + 3) / 4;
    k3b<<<blocks, 256, 0, stream>>>(ws_a, ws_asum, src, dst, ws_hq, ws_agg, e);
  }
  {
    int total = n * 64;
    k4<<<(total + 255) / 256, 256, 0, stream>>>(h_E, ws_agg, bp_node, out0,
                                                total);
  }
}

// Round 6
// 772.041 us; speedup vs baseline: 1.1302x; 1.1302x over previous
//
#include <hip/hip_runtime.h>
#include <math.h>

#define NEG_SLOPE 0.2f

typedef __bf16 bf16x8 __attribute__((ext_vector_type(8)));
typedef float f32x4 __attribute__((ext_vector_type(4)));

// f32 -> bf16 bits, round-to-nearest-even
__device__ __forceinline__ ushort f2bf(float x) {
  union { float f; unsigned u; } v; v.f = x;
  unsigned r = v.u + 0x7fffu + ((v.u >> 16) & 1u);
  return (ushort)(r >> 16);
}
__device__ __forceinline__ float bf2f(ushort b) {
  union { unsigned u; float f; } v; v.u = (unsigned)b << 16;
  return v.f;
}

// LDS swizzle for [32][512B] rows (f-tile)
__device__ __forceinline__ int swz(int m) {
  return ((m & 7) << 4) | (((m >> 3) & 3) << 7);
}

// atomic float max via int/uint trick (works for mixed signs, init -inf)
__device__ __forceinline__ void atomicMaxF32(float* addr, float val) {
  if (val >= 0.f) {
    atomicMax((int*)addr, __float_as_int(val));
  } else {
    atomicMin((unsigned int*)addr, __float_as_uint(val));
  }
}

// ---------------- K0: init emax=-inf, asum=0, agg=0 ----------------
__global__ void k_init(float* __restrict__ emax, float* __restrict__ asum,
                       float* __restrict__ agg, int n) {
  int i = blockIdx.x * 256 + threadIdx.x;
  if (i < n * 4) { emax[i] = -INFINITY; asum[i] = 0.f; }
  if (i < n * 64) agg[i] = 0.f;
}

// ---------------- K prep: build concatenated bf16 weights ----------------
// WcatT[c][k], c<256, k<192, k-order [Wfij(0..63) | Wni(64..127) | Wnj(128..191)]
// WpeT[n][k] = Wpe[k][n]  (k<256, n<64)
__global__ void k_prep(const float* __restrict__ Wfij,
                       const float* __restrict__ Wni,
                       const float* __restrict__ Wnj,
                       const float* __restrict__ Wpe,
                       ushort* __restrict__ WcatT, ushort* __restrict__ WpeT) {
  int i = blockIdx.x * 256 + threadIdx.x;
  if (i < 49152) {
    int c = i / 192, k = i % 192;
    float v = (k < 64) ? Wfij[k * 256 + c]
            : (k < 128) ? Wni[(k - 64) * 256 + c]
                        : Wnj[(k - 128) * 256 + c];
    WcatT[c * 192 + k] = f2bf(v);
  }
  if (i < 16384) {
    int k2 = i >> 6, n2 = i & 63;  // Wpe[k2][n2]
    WpeT[n2 * 256 + k2] = f2bf(Wpe[i]);
  }
}

// ---------------- K1: node transforms: hE_bf(bf16), hq(bf16) ----------------
// hp = hE@Wnode + bnode; hq[n,h,:] = hp[n,h,:] @ Wpn[h*64:(h+1)*64,:]
__global__ __launch_bounds__(256) void k_node(
    const float* __restrict__ hE,
    const float* __restrict__ Wnode, const float* __restrict__ bnode,
    const float* __restrict__ Wpn,
    ushort* __restrict__ hE_bf, ushort* __restrict__ hq, int n) {
  __shared__ float hEt[64 * 36];    // transposed [k][m], stride 36 (pad)
  __shared__ float hpl[32 * 260];   // hp tile [m][c], stride 260 (pad)
  const int tid = threadIdx.x;
  const int n0 = blockIdx.x * 32;

#pragma unroll
  for (int i = 0; i < 8; ++i) {
    int flat = tid + i * 256;
    int m = flat >> 6, k = flat & 63;
    float v = (n0 + m < n) ? hE[(size_t)(n0 + m) * 64 + k] : 0.f;
    hEt[k * 36 + m] = v;
    if (n0 + m < n) hE_bf[(size_t)(n0 + m) * 64 + k] = f2bf(v);
  }
  __syncthreads();

  const int tm = tid >> 5, tc = tid & 31, c0 = tc * 8;

  // hp pass
  {
    float acc[4][8];
#pragma unroll
    for (int mm = 0; mm < 4; ++mm)
#pragma unroll
      for (int j = 0; j < 8; ++j) acc[mm][j] = 0.f;

    for (int k = 0; k < 64; ++k) {
      float4 h4 = *(const float4*)&hEt[k * 36 + tm * 4];
      float4 w0 = *(const float4*)&Wnode[k * 256 + c0];
      float4 w1 = *(const float4*)&Wnode[k * 256 + c0 + 4];
      float hv[4] = {h4.x, h4.y, h4.z, h4.w};
      float wv[8] = {w0.x, w0.y, w0.z, w0.w, w1.x, w1.y, w1.z, w1.w};
#pragma unroll
      for (int mm = 0; mm < 4; ++mm)
#pragma unroll
        for (int j = 0; j < 8; ++j) acc[mm][j] += hv[mm] * wv[j];
    }
#pragma unroll
    for (int mm = 0; mm < 4; ++mm) {
      int m = tm * 4 + mm;
#pragma unroll
      for (int j = 0; j < 8; ++j)
        hpl[m * 260 + c0 + j] = acc[mm][j] + bnode[c0 + j];
    }
  }
  __syncthreads();

  // hq pass: per-head 64x64 projection. col c0+j lives in head hh.
  const int hh = tc >> 3, dc0 = (tc & 7) * 8;
  float acc[4][8];
#pragma unroll
  for (int mm = 0; mm < 4; ++mm)
#pragma unroll
    for (int j = 0; j < 8; ++j) acc[mm][j] = 0.f;

  for (int k = 0; k < 64; ++k) {
    float4 w0 = *(const float4*)&Wpn[(size_t)(hh * 64 + k) * 64 + dc0];
    float4 w1 = *(const float4*)&Wpn[(size_t)(hh * 64 + k) * 64 + dc0 + 4];
    float wv[8] = {w0.x, w0.y, w0.z, w0.w, w1.x, w1.y, w1.z, w1.w};
#pragma unroll
    for (int mm = 0; mm < 4; ++mm) {
      float hv = hpl[(tm * 4 + mm) * 260 + hh * 64 + k];
#pragma unroll
      for (int j = 0; j < 8; ++j) acc[mm][j] += hv * wv[j];
    }
  }
#pragma unroll
  for (int mm = 0; mm < 4; ++mm) {
    int m = tm * 4 + mm;
    if (n0 + m < n) {
      ushort u[8];
#pragma unroll
      for (int j = 0; j < 8; ++j) u[j] = f2bf(acc[mm][j]);
      *(uint4*)&hq[(size_t)(n0 + m) * 256 + c0] = *(const uint4*)u;
    }
  }
}

// ---------------- K2: edge kernel (K=192 fused GEMM1) ----------------
// f = leaky([hH | hE[src] | hE[dst]] @ [Wfij;Wni;Wnj]); e = head-dots(f,attn);
// atomicMax emax; out1 = hH + f@Wpe + bpe.
// Tile: 32 edges, 4 waves; wave w owns GEMM1 col-slab [w*64,(w+1)*64) (=head w)
// and GEMM2 cols [w*16,(w+1)*16).
// LDS: A-tile [32 rows][192 k] bf16 (384B rows, XOR-swizzled 16B units within
// each 128B section) + f-tile [32][256] bf16 (512B rows, swz()).
// Gather working set = hE_bf (6.4MB, ~L2-resident) instead of ni/nj (51MB).
__global__ __launch_bounds__(256, 4) void k_edge(
    const float* __restrict__ hH,
    const int* __restrict__ src, const int* __restrict__ dst,
    const ushort* __restrict__ WcatT,  // [256][192] bf16
    const float* __restrict__ attn,
    const ushort* __restrict__ WpeT,   // [64][256] bf16
    const float* __restrict__ bpe,
    const ushort* __restrict__ hE_bf,  // [n][64] bf16
    float* __restrict__ e_ws, float* __restrict__ emax,
    float* __restrict__ out1) {
  __shared__ __align__(16) char smem[32 * 384 + 32 * 512];  // 28672B
  char* ab = smem;            // A-tile
  char* fb = smem + 12288;    // f-tile

  const int tid = threadIdx.x;
  const int e0 = blockIdx.x * 32;

  // ---- Phase 0: stage A-tile = [hH | hE_src | hE_dst] as bf16
  {
    int m = tid >> 3, s = tid & 7;
    int sn = src[e0 + m], dn = dst[e0 + m];
    char* arow = ab + m * 384;
    int swm = (m & 7) << 4;
    // hH (f32 -> bf16), 16B slot s
    const float* p = hH + (size_t)(e0 + m) * 64 + s * 8;
    float4 x = *(const float4*)p;
    float4 y = *(const float4*)(p + 4);
    ushort u[8] = {f2bf(x.x), f2bf(x.y), f2bf(x.z), f2bf(x.w),
                   f2bf(y.x), f2bf(y.y), f2bf(y.z), f2bf(y.w)};
    *(uint4*)(arow + ((s * 16) ^ swm)) = *(const uint4*)u;
    // hE[src], hE[dst] (bf16 gathers, 16B each)
    *(uint4*)(arow + (128 + ((s * 16) ^ swm))) =
        *(const uint4*)(hE_bf + (size_t)sn * 64 + s * 8);
    *(uint4*)(arow + (256 + ((s * 16) ^ swm))) =
        *(const uint4*)(hE_bf + (size_t)dn * 64 + s * 8);
  }
  __syncthreads();

  const int w = tid >> 6, l = tid & 63;
  const int lr = l & 15, lk = l >> 4;
  const int swa = (lr & 7) << 4;

  // ---- GEMM1: f_pre = A(32x192) @ Wcat(192x256), wave slab [w*64,(w+1)*64)
  f32x4 acc[2][4];
#pragma unroll
  for (int mt = 0; mt < 2; ++mt)
#pragma unroll
    for (int nt = 0; nt < 4; ++nt) acc[mt][nt] = (f32x4){0.f, 0.f, 0.f, 0.f};

#pragma unroll
  for (int ks = 0; ks < 6; ++ks) {
    int sec = (ks >> 1) << 7;               // 128B section base (k*2 high bits)
    int off = ((ks & 1) << 6) | (lk << 4);  // 0..127 within section
    bf16x8 a0 = *(const bf16x8*)(ab + lr * 384 + sec + (off ^ swa));
    bf16x8 a1 = *(const bf16x8*)(ab + (16 + lr) * 384 + sec + (off ^ swa));
#pragma unroll
    for (int nt = 0; nt < 4; ++nt) {
      bf16x8 b = *(const bf16x8*)(WcatT +
          (size_t)(w * 64 + nt * 16 + lr) * 192 + ks * 32 + lk * 8);
      acc[0][nt] =
          __builtin_amdgcn_mfma_f32_16x16x32_bf16(a0, b, acc[0][nt], 0, 0, 0);
      acc[1][nt] =
          __builtin_amdgcn_mfma_f32_16x16x32_bf16(a1, b, acc[1][nt], 0, 0, 0);
    }
  }

  // ---- leaky, logits, f -> bf16 f-tile
  float av[4];
#pragma unroll
  for (int nt = 0; nt < 4; ++nt) av[nt] = attn[w * 64 + nt * 16 + lr];

#pragma unroll
  for (int mt = 0; mt < 2; ++mt) {
#pragma unroll
    for (int r = 0; r < 4; ++r) {
      int m = mt * 16 + lk * 4 + r;
      char* rowp = fb + m * 512;
      int sw = swz(m);
      float p = 0.f;
#pragma unroll
      for (int nt = 0; nt < 4; ++nt) {
        int c = w * 64 + nt * 16 + lr;
        float v = acc[mt][nt][r];
        v = (v >= 0.f) ? v : NEG_SLOPE * v;
        p += v * av[nt];
        *(ushort*)(rowp + ((c * 2) ^ sw)) = f2bf(v);
      }
      p += __shfl_xor(p, 1);
      p += __shfl_xor(p, 2);
      p += __shfl_xor(p, 4);
      p += __shfl_xor(p, 8);
      if (lr == 0) {
        e_ws[(size_t)(e0 + m) * 4 + w] = p;
        atomicMaxF32(&emax[(size_t)dst[e0 + m] * 4 + w], p);
      }
    }
  }
  __syncthreads();

  // ---- GEMM2: out1 = f @ Wpe; wave w owns cols [w*16,(w+1)*16)
  f32x4 acc2[2];
  acc2[0] = (f32x4){0.f, 0.f, 0.f, 0.f};
  acc2[1] = (f32x4){0.f, 0.f, 0.f, 0.f};
  const ushort* bpW = WpeT + (size_t)(w * 16 + lr) * 256;
  const int sw0 = swz(lr), sw1 = swz(16 + lr);
#pragma unroll
  for (int ks = 0; ks < 8; ++ks) {
    int ko = (ks * 32 + lk * 8) * 2;
    bf16x8 b = *(const bf16x8*)(bpW + ks * 32 + lk * 8);
    bf16x8 a0 = *(const bf16x8*)(fb + lr * 512 + (ko ^ sw0));
    bf16x8 a1 = *(const bf16x8*)(fb + (16 + lr) * 512 + (ko ^ sw1));
    acc2[0] = __builtin_amdgcn_mfma_f32_16x16x32_bf16(a0, b, acc2[0], 0, 0, 0);
    acc2[1] = __builtin_amdgcn_mfma_f32_16x16x32_bf16(a1, b, acc2[1], 0, 0, 0);
  }

  // epilogue: + hH (from A-tile, bf16) + bpe
  float bpv = bpe[w * 16 + lr];
#pragma unroll
  for (int mt = 0; mt < 2; ++mt)
#pragma unroll
    for (int r = 0; r < 4; ++r) {
      int m = mt * 16 + lk * 4 + r;
      int swm = (m & 7) << 4;
      ushort h =
          *(const ushort*)(ab + m * 384 + ((((w * 16 + lr) * 2)) ^ swm));
      size_t idx = (size_t)(e0 + m) * 64 + w * 16 + lr;
      out1[idx] = acc2[mt][r] + bf2f(h) + bpv;
    }
}

// ---------------- K3a: a = exp(e - emax[dst]); asum += a ----------------
__global__ void k3a(const float* __restrict__ e_ws, const int* __restrict__ dst,
                    const float* __restrict__ emax, float* __restrict__ a_ws,
                    float* __restrict__ asum, int E4) {
  int gid = blockIdx.x * 256 + threadIdx.x;
  if (gid >= E4) return;
  int e = gid >> 2, h = gid & 3;
  int dn = dst[e];
  float av = expf(e_ws[gid] - emax[dn * 4 + h]);
  a_ws[gid] = av;
  atomicAdd(&asum[dn * 4 + h], av);
}

// ---------------- K3b: agg[dst] += sum_h (a/asum) * hq[src,h,:] ----------------
__global__ __launch_bounds__(256) void k3b(
    const float* __restrict__ a_ws, const float* __restrict__ asum,
    const int* __restrict__ src, const int* __restrict__ dst,
    const ushort* __restrict__ hq, float* __restrict__ agg, int E) {
  int e = blockIdx.x * 4 + (threadIdx.x >> 6);
  if (e >= E) return;
  int d = threadIdx.x & 63;
  int sn = src[e], dn = dst[e];
  float w0 = a_ws[e * 4 + 0] / asum[dn * 4 + 0];
  float w1 = a_ws[e * 4 + 1] / asum[dn * 4 + 1];
  float w2 = a_ws[e * 4 + 2] / asum[dn * 4 + 2];
  float w3 = a_ws[e * 4 + 3] / asum[dn * 4 + 3];
  const ushort* hqp = hq + (size_t)sn * 256;
  float y = w0 * bf2f(hqp[d]) + w1 * bf2f(hqp[64 + d]) +
            w2 * bf2f(hqp[128 + d]) + w3 * bf2f(hqp[192 + d]);
  atomicAdd(&agg[(size_t)dn * 64 + d], y);
}

// ---------------- K4: out0 = hE + agg + bp_node ----------------
__global__ void k4(const float* __restrict__ hE, const float* __restrict__ agg,
                   const float* __restrict__ bpn, float* __restrict__ out0,
                   int ND) {
  int i = blockIdx.x * 256 + threadIdx.x;
  if (i < ND) out0[i] = hE[i] + agg[i] + bpn[i & 63];
}

extern "C" void kernel_launch(void* const* d_in, const int* in_sizes, int n_in,
                              void* d_out, int out_size, void* d_ws, size_t ws_size,
                              hipStream_t stream) {
  const float* h_E    = (const float*)d_in[0];
  const float* h_H    = (const float*)d_in[1];
  const int*   src    = (const int*)d_in[2];
  const int*   dst    = (const int*)d_in[3];
  const float* W_node = (const float*)d_in[4];
  const float* b_node = (const float*)d_in[5];
  const float* W_ni   = (const float*)d_in[6];
  const float* W_nj   = (const float*)d_in[7];
  const float* W_fij  = (const float*)d_in[8];
  const float* attn   = (const float*)d_in[9];
  const float* Wp_node= (const float*)d_in[10];
  const float* bp_node= (const float*)d_in[11];
  const float* Wp_edge= (const float*)d_in[12];
  const float* bp_edge= (const float*)d_in[13];

  const int n = in_sizes[0] / 64;   // 50000 nodes
  const int e = in_sizes[1] / 64;   // 800000 edges

  // workspace layout
  ushort* ws_hEbf = (ushort*)d_ws;                      // n*64 bf16
  ushort* ws_hq   = ws_hEbf + (size_t)n * 64;           // n*256 bf16
  float*  ws_e    = (float*)(ws_hq + (size_t)n * 256);  // e*4
  float*  ws_a    = ws_e + (size_t)e * 4;               // e*4
  float*  ws_emax = ws_a + (size_t)e * 4;               // n*4
  float*  ws_asum = ws_emax + (size_t)n * 4;            // n*4
  float*  ws_agg  = ws_asum + (size_t)n * 4;            // n*64
  ushort* ws_Wcat = (ushort*)(ws_agg + (size_t)n * 64); // 256*192 bf16
  ushort* ws_WpeT = ws_Wcat + 49152;                    // 64*256 bf16

  float* out0 = (float*)d_out;               // (n,64)
  float* out1 = out0 + (size_t)n * 64;       // (e,64)

  {
    int total = n * 64;
    k_init<<<(total + 255) / 256, 256, 0, stream>>>(ws_emax, ws_asum, ws_agg, n);
  }
  k_prep<<<192, 256, 0, stream>>>(W_fij, W_ni, W_nj, Wp_edge, ws_Wcat, ws_WpeT);
  {
    int blocks = (n + 31) / 32;
    k_node<<<blocks, 256, 0, stream>>>(h_E, W_node, b_node, Wp_node,
                                       ws_hEbf, ws_hq, n);
  }
  {
    int blocks = e / 32;  // E=800000 divisible by 32
    k_edge<<<blocks, 256, 0, stream>>>(h_H, src, dst, ws_Wcat, attn, ws_WpeT,
                                       bp_edge, ws_hEbf, ws_e, ws_emax, out1);
  }
  {
    int total = e * 4;
    k3a<<<(total + 255) / 256, 256, 0, stream>>>(ws_e, dst, ws_emax, ws_a,
                                                 ws_asum, total);
  }
  {
    int blocks = (e + 3) / 4;
    k3b<<<blocks, 256, 0, stream>>>(ws_a, ws_asum, src, dst, ws_hq, ws_agg, e);
  }
  {
    int total = n * 64;
    k4<<<(total + 255) / 256, 256, 0, stream>>>(h_E, ws_agg, bp_node, out0,
                                                total);
  }
}

// Round 7
// 692.544 us; speedup vs baseline: 1.2600x; 1.1148x over previous
//
#include <hip/hip_runtime.h>
#include <math.h>

#define NEG_SLOPE 0.2f

typedef __bf16 bf16x8 __attribute__((ext_vector_type(8)));
typedef float f32x4 __attribute__((ext_vector_type(4)));

// f32 -> bf16 bits, round-to-nearest-even
__device__ __forceinline__ ushort f2bf(float x) {
  union { float f; unsigned u; } v; v.f = x;
  unsigned r = v.u + 0x7fffu + ((v.u >> 16) & 1u);
  return (ushort)(r >> 16);
}
__device__ __forceinline__ float bf2f(ushort b) {
  union { unsigned u; float f; } v; v.u = (unsigned)b << 16;
  return v.f;
}

// LDS swizzle for [32][512B] rows (f-tile)
__device__ __forceinline__ int swz(int m) {
  return ((m & 7) << 4) | (((m >> 3) & 3) << 7);
}

// atomic float max via int/uint trick (works for mixed signs, init -inf)
__device__ __forceinline__ void atomicMaxF32(float* addr, float val) {
  if (val >= 0.f) {
    atomicMax((int*)addr, __float_as_int(val));
  } else {
    atomicMin((unsigned int*)addr, __float_as_uint(val));
  }
}

// ---------------- K0: init emax=-inf, asum=0, agg=0 ----------------
__global__ void k_init(float* __restrict__ emax, float* __restrict__ asum,
                       float* __restrict__ agg, int n) {
  int i = blockIdx.x * 256 + threadIdx.x;
  if (i < n * 4) { emax[i] = -INFINITY; asum[i] = 0.f; }
  if (i < n * 64) agg[i] = 0.f;
}

// ---------------- K prep: build concatenated bf16 weights ----------------
// WcatT[c][k], c<256, k<192, k-order [Wfij(0..63) | Wni(64..127) | Wnj(128..191)]
// WpeT[n][k] = Wpe[k][n]  (k<256, n<64)
__global__ void k_prep(const float* __restrict__ Wfij,
                       const float* __restrict__ Wni,
                       const float* __restrict__ Wnj,
                       const float* __restrict__ Wpe,
                       ushort* __restrict__ WcatT, ushort* __restrict__ WpeT) {
  int i = blockIdx.x * 256 + threadIdx.x;
  if (i < 49152) {
    int c = i / 192, k = i % 192;
    float v = (k < 64) ? Wfij[k * 256 + c]
            : (k < 128) ? Wni[(k - 64) * 256 + c]
                        : Wnj[(k - 128) * 256 + c];
    WcatT[c * 192 + k] = f2bf(v);
  }
  if (i < 16384) {
    int k2 = i >> 6, n2 = i & 63;  // Wpe[k2][n2]
    WpeT[n2 * 256 + k2] = f2bf(Wpe[i]);
  }
}

// ---------------- K1: node transforms: hE_bf(bf16), hq(bf16) ----------------
__global__ __launch_bounds__(256) void k_node(
    const float* __restrict__ hE,
    const float* __restrict__ Wnode, const float* __restrict__ bnode,
    const float* __restrict__ Wpn,
    ushort* __restrict__ hE_bf, ushort* __restrict__ hq, int n) {
  __shared__ float hEt[64 * 36];    // transposed [k][m], stride 36 (pad)
  __shared__ float hpl[32 * 260];   // hp tile [m][c], stride 260 (pad)
  const int tid = threadIdx.x;
  const int n0 = blockIdx.x * 32;

#pragma unroll
  for (int i = 0; i < 8; ++i) {
    int flat = tid + i * 256;
    int m = flat >> 6, k = flat & 63;
    float v = (n0 + m < n) ? hE[(size_t)(n0 + m) * 64 + k] : 0.f;
    hEt[k * 36 + m] = v;
    if (n0 + m < n) hE_bf[(size_t)(n0 + m) * 64 + k] = f2bf(v);
  }
  __syncthreads();

  const int tm = tid >> 5, tc = tid & 31, c0 = tc * 8;

  // hp pass
  {
    float acc[4][8];
#pragma unroll
    for (int mm = 0; mm < 4; ++mm)
#pragma unroll
      for (int j = 0; j < 8; ++j) acc[mm][j] = 0.f;

    for (int k = 0; k < 64; ++k) {
      float4 h4 = *(const float4*)&hEt[k * 36 + tm * 4];
      float4 w0 = *(const float4*)&Wnode[k * 256 + c0];
      float4 w1 = *(const float4*)&Wnode[k * 256 + c0 + 4];
      float hv[4] = {h4.x, h4.y, h4.z, h4.w};
      float wv[8] = {w0.x, w0.y, w0.z, w0.w, w1.x, w1.y, w1.z, w1.w};
#pragma unroll
      for (int mm = 0; mm < 4; ++mm)
#pragma unroll
        for (int j = 0; j < 8; ++j) acc[mm][j] += hv[mm] * wv[j];
    }
#pragma unroll
    for (int mm = 0; mm < 4; ++mm) {
      int m = tm * 4 + mm;
#pragma unroll
      for (int j = 0; j < 8; ++j)
        hpl[m * 260 + c0 + j] = acc[mm][j] + bnode[c0 + j];
    }
  }
  __syncthreads();

  // hq pass: per-head 64x64 projection. col c0+j lives in head hh.
  const int hh = tc >> 3, dc0 = (tc & 7) * 8;
  float acc[4][8];
#pragma unroll
  for (int mm = 0; mm < 4; ++mm)
#pragma unroll
    for (int j = 0; j < 8; ++j) acc[mm][j] = 0.f;

  for (int k = 0; k < 64; ++k) {
    float4 w0 = *(const float4*)&Wpn[(size_t)(hh * 64 + k) * 64 + dc0];
    float4 w1 = *(const float4*)&Wpn[(size_t)(hh * 64 + k) * 64 + dc0 + 4];
    float wv[8] = {w0.x, w0.y, w0.z, w0.w, w1.x, w1.y, w1.z, w1.w};
#pragma unroll
    for (int mm = 0; mm < 4; ++mm) {
      float hv = hpl[(tm * 4 + mm) * 260 + hh * 64 + k];
#pragma unroll
      for (int j = 0; j < 8; ++j) acc[mm][j] += hv * wv[j];
    }
  }
#pragma unroll
  for (int mm = 0; mm < 4; ++mm) {
    int m = tm * 4 + mm;
    if (n0 + m < n) {
      ushort u[8];
#pragma unroll
      for (int j = 0; j < 8; ++j) u[j] = f2bf(acc[mm][j]);
      *(uint4*)&hq[(size_t)(n0 + m) * 256 + c0] = *(const uint4*)u;
    }
  }
}

// ---------------- K2: edge kernel (persistent, register-resident weights) ----
// f = leaky([hH | hE[src] | hE[dst]] @ [Wfij;Wni;Wnj]); e = head-dots(f,attn);
// atomicMax emax; out1 = hH + f@Wpe + bpe.
// 512 persistent blocks (2/CU). Per wave: ALL weight B-fragments hoisted into
// registers ONCE (bw1: 24 frags = 96 VGPR, bw2: 8 frags = 32 VGPR) — the
// inner tile loop has ZERO global weight traffic, eliminating the serialized
// per-tile L2 latency chain that pinned r2-r6 at ~500us (VGPR=52 showed the
// compiler couldn't hoist these itself).
__global__ __launch_bounds__(256, 2) void k_edge(
    const float* __restrict__ hH,
    const int* __restrict__ src, const int* __restrict__ dst,
    const ushort* __restrict__ WcatT,  // [256][192] bf16
    const float* __restrict__ attn,
    const ushort* __restrict__ WpeT,   // [64][256] bf16
    const float* __restrict__ bpe,
    const ushort* __restrict__ hE_bf,  // [n][64] bf16
    float* __restrict__ e_ws, float* __restrict__ emax,
    float* __restrict__ out1, int ntiles) {
  __shared__ __align__(16) char smem[32 * 384 + 32 * 512];  // 28672B
  char* ab = smem;            // A-tile [32][384B]
  char* fb = smem + 12288;    // f-tile [32][512B]

  const int tid = threadIdx.x;
  const int w = tid >> 6, l = tid & 63;
  const int lr = l & 15, lk = l >> 4;
  const int swa = (lr & 7) << 4;
  const int stm = tid >> 3, sts = tid & 7;  // staging role: 8 thr/edge

  // ---- one-time: hoist all weights for this wave into registers
  bf16x8 bw1[6][4];
#pragma unroll
  for (int ks = 0; ks < 6; ++ks)
#pragma unroll
    for (int nt = 0; nt < 4; ++nt)
      bw1[ks][nt] = *(const bf16x8*)(WcatT +
          (size_t)(w * 64 + nt * 16 + lr) * 192 + ks * 32 + lk * 8);
  bf16x8 bw2[8];
#pragma unroll
  for (int ks = 0; ks < 8; ++ks)
    bw2[ks] = *(const bf16x8*)(WpeT +
        (size_t)(w * 16 + lr) * 256 + ks * 32 + lk * 8);
  float av[4];
#pragma unroll
  for (int nt = 0; nt < 4; ++nt) av[nt] = attn[w * 64 + nt * 16 + lr];
  const float bpv = bpe[w * 16 + lr];
  const int sw0 = swz(lr), sw1 = swz(16 + lr);

  for (int tile = blockIdx.x; tile < ntiles; tile += gridDim.x) {
    const int e0 = tile * 32;

    // ---- Phase 0: stage A-tile = [hH | hE_src | hE_dst] as bf16
    {
      int sn = src[e0 + stm], dn = dst[e0 + stm];
      char* arow = ab + stm * 384;
      int swm = (stm & 7) << 4;
      const float* p = hH + (size_t)(e0 + stm) * 64 + sts * 8;
      float4 x = *(const float4*)p;
      float4 y = *(const float4*)(p + 4);
      ushort u[8] = {f2bf(x.x), f2bf(x.y), f2bf(x.z), f2bf(x.w),
                     f2bf(y.x), f2bf(y.y), f2bf(y.z), f2bf(y.w)};
      *(uint4*)(arow + ((sts * 16) ^ swm)) = *(const uint4*)u;
      *(uint4*)(arow + (128 + ((sts * 16) ^ swm))) =
          *(const uint4*)(hE_bf + (size_t)sn * 64 + sts * 8);
      *(uint4*)(arow + (256 + ((sts * 16) ^ swm))) =
          *(const uint4*)(hE_bf + (size_t)dn * 64 + sts * 8);
    }
    __syncthreads();

    // ---- GEMM1: f_pre = A(32x192) @ Wcat(192x256), wave slab [w*64,(w+1)*64)
    f32x4 acc[2][4];
#pragma unroll
    for (int mt = 0; mt < 2; ++mt)
#pragma unroll
      for (int nt = 0; nt < 4; ++nt) acc[mt][nt] = (f32x4){0.f, 0.f, 0.f, 0.f};

#pragma unroll
    for (int ks = 0; ks < 6; ++ks) {
      int sec = (ks >> 1) << 7;               // 128B section base
      int off = ((ks & 1) << 6) | (lk << 4);  // 0..127 within section
      bf16x8 a0 = *(const bf16x8*)(ab + lr * 384 + sec + (off ^ swa));
      bf16x8 a1 = *(const bf16x8*)(ab + (16 + lr) * 384 + sec + (off ^ swa));
#pragma unroll
      for (int nt = 0; nt < 4; ++nt) {
        acc[0][nt] = __builtin_amdgcn_mfma_f32_16x16x32_bf16(
            a0, bw1[ks][nt], acc[0][nt], 0, 0, 0);
        acc[1][nt] = __builtin_amdgcn_mfma_f32_16x16x32_bf16(
            a1, bw1[ks][nt], acc[1][nt], 0, 0, 0);
      }
    }

    // ---- leaky, logits, f -> bf16 f-tile
#pragma unroll
    for (int mt = 0; mt < 2; ++mt) {
#pragma unroll
      for (int r = 0; r < 4; ++r) {
        int m = mt * 16 + lk * 4 + r;
        char* rowp = fb + m * 512;
        int sw = swz(m);
        float p = 0.f;
#pragma unroll
        for (int nt = 0; nt < 4; ++nt) {
          int c = w * 64 + nt * 16 + lr;
          float v = acc[mt][nt][r];
          v = (v >= 0.f) ? v : NEG_SLOPE * v;
          p += v * av[nt];
          *(ushort*)(rowp + ((c * 2) ^ sw)) = f2bf(v);
        }
        p += __shfl_xor(p, 1);
        p += __shfl_xor(p, 2);
        p += __shfl_xor(p, 4);
        p += __shfl_xor(p, 8);
        if (lr == 0) {
          e_ws[(size_t)(e0 + m) * 4 + w] = p;
          atomicMaxF32(&emax[(size_t)dst[e0 + m] * 4 + w], p);
        }
      }
    }
    __syncthreads();

    // ---- GEMM2: out1 = f @ Wpe; wave w owns cols [w*16,(w+1)*16)
    f32x4 acc2[2];
    acc2[0] = (f32x4){0.f, 0.f, 0.f, 0.f};
    acc2[1] = (f32x4){0.f, 0.f, 0.f, 0.f};
#pragma unroll
    for (int ks = 0; ks < 8; ++ks) {
      int ko = (ks * 32 + lk * 8) * 2;
      bf16x8 a0 = *(const bf16x8*)(fb + lr * 512 + (ko ^ sw0));
      bf16x8 a1 = *(const bf16x8*)(fb + (16 + lr) * 512 + (ko ^ sw1));
      acc2[0] =
          __builtin_amdgcn_mfma_f32_16x16x32_bf16(a0, bw2[ks], acc2[0], 0, 0, 0);
      acc2[1] =
          __builtin_amdgcn_mfma_f32_16x16x32_bf16(a1, bw2[ks], acc2[1], 0, 0, 0);
    }

    // epilogue: + hH (from A-tile, bf16) + bpe
#pragma unroll
    for (int mt = 0; mt < 2; ++mt)
#pragma unroll
      for (int r = 0; r < 4; ++r) {
        int m = mt * 16 + lk * 4 + r;
        int swm = (m & 7) << 4;
        ushort h =
            *(const ushort*)(ab + m * 384 + ((((w * 16 + lr) * 2)) ^ swm));
        size_t idx = (size_t)(e0 + m) * 64 + w * 16 + lr;
        out1[idx] = acc2[mt][r] + bf2f(h) + bpv;
      }
    __syncthreads();  // protect LDS before next tile's staging
  }
}

// ---------------- K3a: a = exp(e - emax[dst]); asum += a ----------------
__global__ void k3a(const float* __restrict__ e_ws, const int* __restrict__ dst,
                    const float* __restrict__ emax, float* __restrict__ a_ws,
                    float* __restrict__ asum, int E4) {
  int gid = blockIdx.x * 256 + threadIdx.x;
  if (gid >= E4) return;
  int e = gid >> 2, h = gid & 3;
  int dn = dst[e];
  float av = expf(e_ws[gid] - emax[dn * 4 + h]);
  a_ws[gid] = av;
  atomicAdd(&asum[dn * 4 + h], av);
}

// ---------------- K3b: agg[dst] += sum_h (a/asum) * hq[src,h,:] ----------------
__global__ __launch_bounds__(256) void k3b(
    const float* __restrict__ a_ws, const float* __restrict__ asum,
    const int* __restrict__ src, const int* __restrict__ dst,
    const ushort* __restrict__ hq, float* __restrict__ agg, int E) {
  int e = blockIdx.x * 4 + (threadIdx.x >> 6);
  if (e >= E) return;
  int d = threadIdx.x & 63;
  int sn = src[e], dn = dst[e];
  float w0 = a_ws[e * 4 + 0] / asum[dn * 4 + 0];
  float w1 = a_ws[e * 4 + 1] / asum[dn * 4 + 1];
  float w2 = a_ws[e * 4 + 2] / asum[dn * 4 + 2];
  float w3 = a_ws[e * 4 + 3] / asum[dn * 4 + 3];
  const ushort* hqp = hq + (size_t)sn * 256;
  float y = w0 * bf2f(hqp[d]) + w1 * bf2f(hqp[64 + d]) +
            w2 * bf2f(hqp[128 + d]) + w3 * bf2f(hqp[192 + d]);
  atomicAdd(&agg[(size_t)dn * 64 + d], y);
}

// ---------------- K4: out0 = hE + agg + bp_node ----------------
__global__ void k4(const float* __restrict__ hE, const float* __restrict__ agg,
                   const float* __restrict__ bpn, float* __restrict__ out0,
                   int ND) {
  int i = blockIdx.x * 256 + threadIdx.x;
  if (i < ND) out0[i] = hE[i] + agg[i] + bpn[i & 63];
}

extern "C" void kernel_launch(void* const* d_in, const int* in_sizes, int n_in,
                              void* d_out, int out_size, void* d_ws, size_t ws_size,
                              hipStream_t stream) {
  const float* h_E    = (const float*)d_in[0];
  const float* h_H    = (const float*)d_in[1];
  const int*   src    = (const int*)d_in[2];
  const int*   dst    = (const int*)d_in[3];
  const float* W_node = (const float*)d_in[4];
  const float* b_node = (const float*)d_in[5];
  const float* W_ni   = (const float*)d_in[6];
  const float* W_nj   = (const float*)d_in[7];
  const float* W_fij  = (const float*)d_in[8];
  const float* attn   = (const float*)d_in[9];
  const float* Wp_node= (const float*)d_in[10];
  const float* bp_node= (const float*)d_in[11];
  const float* Wp_edge= (const float*)d_in[12];
  const float* bp_edge= (const float*)d_in[13];

  const int n = in_sizes[0] / 64;   // 50000 nodes
  const int e = in_sizes[1] / 64;   // 800000 edges

  // workspace layout
  ushort* ws_hEbf = (ushort*)d_ws;                      // n*64 bf16
  ushort* ws_hq   = ws_hEbf + (size_t)n * 64;           // n*256 bf16
  float*  ws_e    = (float*)(ws_hq + (size_t)n * 256);  // e*4
  float*  ws_a    = ws_e + (size_t)e * 4;               // e*4
  float*  ws_emax = ws_a + (size_t)e * 4;               // n*4
  float*  ws_asum = ws_emax + (size_t)n * 4;            // n*4
  float*  ws_agg  = ws_asum + (size_t)n * 4;            // n*64
  ushort* ws_Wcat = (ushort*)(ws_agg + (size_t)n * 64); // 256*192 bf16
  ushort* ws_WpeT = ws_Wcat + 49152;                    // 64*256 bf16

  float* out0 = (float*)d_out;               // (n,64)
  float* out1 = out0 + (size_t)n * 64;       // (e,64)

  {
    int total = n * 64;
    k_init<<<(total + 255) / 256, 256, 0, stream>>>(ws_emax, ws_asum, ws_agg, n);
  }
  k_prep<<<192, 256, 0, stream>>>(W_fij, W_ni, W_nj, Wp_edge, ws_Wcat, ws_WpeT);
  {
    int blocks = (n + 31) / 32;
    k_node<<<blocks, 256, 0, stream>>>(h_E, W_node, b_node, Wp_node,
                                       ws_hEbf, ws_hq, n);
  }
  {
    int ntiles = e / 32;  // E=800000 divisible by 32
    k_edge<<<512, 256, 0, stream>>>(h_H, src, dst, ws_Wcat, attn, ws_WpeT,
                                    bp_edge, ws_hEbf, ws_e, ws_emax, out1,
                                    ntiles);
  }
  {
    int total = e * 4;
    k3a<<<(total + 255) / 256, 256, 0, stream>>>(ws_e, dst, ws_emax, ws_a,
                                                 ws_asum, total);
  }
  {
    int blocks = (e + 3) / 4;
    k3b<<<blocks, 256, 0, stream>>>(ws_a, ws_asum, src, dst, ws_hq, ws_agg, e);
  }
  {
    int total = n * 64;
    k4<<<(total + 255) / 256, 256, 0, stream>>>(h_E, ws_agg, bp_node, out0,
                                                total);
  }
}